// Round 2
// baseline (771.698 us; speedup 1.0000x reference)
//
#include <hip/hip_runtime.h>

typedef unsigned short ushort_t;
typedef short short8 __attribute__((ext_vector_type(8)));
typedef float f32x4 __attribute__((ext_vector_type(4)));

#define M_TOT 16384
#define N_TOT 4096
#define K_TOT 4096

// ---------------- helpers ----------------

__device__ __forceinline__ unsigned short f2bf(float f) {
  unsigned int u = __float_as_uint(f);
  unsigned int r = (u + 0x7fffu + ((u >> 16) & 1u)) >> 16;  // RNE
  return (unsigned short)r;
}

// async global->LDS, 16B per lane. LDS dest is wave-uniform base + lane*16.
__device__ __forceinline__ void gld_lds16(const void* g, void* l) {
  __builtin_amdgcn_global_load_lds(
      (__attribute__((address_space(1))) const unsigned int*)g,
      (__attribute__((address_space(3))) unsigned int*)l, 16, 0, 0);
}

// ---------------- fp32 -> bf16 convert ----------------

__global__ void cvt_bf16_kernel(const float* __restrict__ src,
                                ushort_t* __restrict__ dst, int n8) {
  for (long long i = (long long)blockIdx.x * 256 + threadIdx.x; i < n8;
       i += (long long)gridDim.x * 256) {
    const float4* s = (const float4*)src + i * 2;
    float4 a = s[0], b = s[1];
    union { ushort_t u[8]; uint4 v; } o;
    o.u[0] = f2bf(a.x); o.u[1] = f2bf(a.y); o.u[2] = f2bf(a.z); o.u[3] = f2bf(a.w);
    o.u[4] = f2bf(b.x); o.u[5] = f2bf(b.y); o.u[6] = f2bf(b.z); o.u[7] = f2bf(b.w);
    ((uint4*)dst)[i] = o.v;
  }
}

// ---------------- h[g][m][r] = sum_i xb[g*1024+m][i] * A[g][r][i] ----------------
// 8 rows per wave, 32 per block; reads bf16 x (halves HBM) and fp32 A (L2-resident).

__global__ __launch_bounds__(256) void lora_h_kernel(
    const ushort_t* __restrict__ xb, const float* __restrict__ lora_a,
    float* __restrict__ h) {
  const int lane = threadIdx.x & 63;
  const int wave = threadIdx.x >> 6;
  const int rowBase = blockIdx.x * 32 + wave * 8;  // 32 | 1024, no group crossing
  const int g = rowBase >> 10;
  const float* A = lora_a + (size_t)g * 16 * K_TOT;

  float acc[8][16] = {};
  for (int i = lane * 2; i < K_TOT; i += 128) {
    float xv[8][2];
#pragma unroll
    for (int r = 0; r < 8; ++r) {
      unsigned int u = *(const unsigned int*)(xb + (size_t)(rowBase + r) * K_TOT + i);
      xv[r][0] = __uint_as_float(u << 16);
      xv[r][1] = __uint_as_float(u & 0xffff0000u);
    }
#pragma unroll
    for (int t = 0; t < 16; ++t) {
      float2 av = *(const float2*)(A + (size_t)t * K_TOT + i);
#pragma unroll
      for (int r = 0; r < 8; ++r)
        acc[r][t] += xv[r][0] * av.x + xv[r][1] * av.y;
    }
  }
#pragma unroll
  for (int r = 0; r < 8; ++r)
#pragma unroll
    for (int t = 0; t < 16; ++t) {
      float v = acc[r][t];
      v += __shfl_xor(v, 32); v += __shfl_xor(v, 16); v += __shfl_xor(v, 8);
      v += __shfl_xor(v, 4);  v += __shfl_xor(v, 2);  v += __shfl_xor(v, 1);
      if (lane == 0) {
        int mloc = (rowBase + r) & 1023;
        h[((size_t)g << 14) + (size_t)mloc * 16 + t] = v;
      }
    }
}

// ---------------- main GEMM: out = Xbf*Wbf^T + bias + h*lb^T ----------------
// 256x256 tile, BK=64, 8 waves (2Mx4N), 8-phase counted-vmcnt schedule (T2+T3+T4+T5).
// LDS: A[2][256][64] + B[2][256][64] bf16 = 128 KiB, XOR-swizzled rows.

#define STAGE_A(kt, buf, hh) do {                                              \
    const ushort_t* _g = aBase + (size_t)((hh) * 128) * K_TOT + (size_t)(kt) * 64; \
    gld_lds16(_g, &lds[(buf) * 16384 + (hh) * 8192 + wave * 512]);             \
    gld_lds16(_g + (size_t)64 * K_TOT,                                         \
              &lds[(buf) * 16384 + (hh) * 8192 + 4096 + wave * 512]);          \
  } while (0)
#define STAGE_B(kt, buf, hh) do {                                              \
    const ushort_t* _g = bBase + (size_t)((hh) * 128) * K_TOT + (size_t)(kt) * 64; \
    gld_lds16(_g, &lds[32768 + (buf) * 16384 + (hh) * 8192 + wave * 512]);     \
    gld_lds16(_g + (size_t)64 * K_TOT,                                         \
              &lds[32768 + (buf) * 16384 + (hh) * 8192 + 4096 + wave * 512]);  \
  } while (0)

#define LDA(buf, mh) do {                                                      \
    _Pragma("unroll") for (int mf = 0; mf < 4; ++mf)                           \
    _Pragma("unroll") for (int kk = 0; kk < 2; ++kk)                           \
      aF[mf][kk] = *(const short8*)(ldsc + (buf) * 32768 + wm * 16384 +        \
                                    (mh) * 8192 + mf * 2048 + frB +            \
                                    (eA ^ (kk << 6)));                         \
  } while (0)
#define LDB(buf, nh) do {                                                      \
    _Pragma("unroll") for (int nf = 0; nf < 2; ++nf)                           \
    _Pragma("unroll") for (int kk = 0; kk < 2; ++kk)                           \
      bF[nh][nf][kk] = *(const short8*)(ldsc + 65536 + (buf) * 32768 +         \
                                        wn * 8192 + (nh) * 4096 + nf * 2048 +  \
                                        frB + (eA ^ (kk << 6)));               \
  } while (0)

#define QUAD(mh, nh) do {                                                      \
    __builtin_amdgcn_s_setprio(1);                                             \
    _Pragma("unroll") for (int mf = 0; mf < 4; ++mf)                           \
    _Pragma("unroll") for (int nf = 0; nf < 2; ++nf)                           \
    _Pragma("unroll") for (int kk = 0; kk < 2; ++kk)                           \
      acc[(mh) * 4 + mf][(nh) * 2 + nf] = __builtin_amdgcn_mfma_f32_16x16x32_bf16( \
          aF[mf][kk], bF[nh][nf][kk], acc[(mh) * 4 + mf][(nh) * 2 + nf], 0, 0, 0); \
    __builtin_amdgcn_s_setprio(0);                                             \
  } while (0)

#define BAR __builtin_amdgcn_s_barrier()
#define VMCNT(n) asm volatile("s_waitcnt vmcnt(" #n ")" ::: "memory")

__global__ __launch_bounds__(512, 2) void gemm_kernel(
    const ushort_t* __restrict__ xb,    // [M][K] bf16
    const ushort_t* __restrict__ wb,    // [N][K] bf16
    const float* __restrict__ bias,     // [N]
    const float* __restrict__ hbuf,     // [16][1024][16] fp32
    const float* __restrict__ lorab,    // [16][4096][16] fp32
    float* __restrict__ out) {          // [M][N] fp32
  __shared__ __align__(16) ushort_t lds[65536];  // 128 KiB

  const int tid = threadIdx.x;
  const int lane = tid & 63;
  const int wave = tid >> 6;
  const int wm = wave >> 2;             // 0..1
  const int wn = wave & 3;              // 0..3
  const int bid = blockIdx.x;
  const int swz = (bid & 7) * 128 + (bid >> 3);   // XCD-aware, bijective (1024%8==0)
  const int by = swz >> 4;              // 0..63 row tile
  const int bx = swz & 15;              // 0..15 col tile
  const int rowBase = by * 256;
  const int colBase = bx * 256;

  // staging: wave covers 8 rows per 1KB chunk; lane l -> row +(l>>3), in-row byte (l&7)*16.
  // inverse-swizzled global col so that read-side XOR finds linear data.
  const int srow = lane >> 3;
  const int scol = ((lane & 7) ^ srow) << 3;
  const ushort_t* aBase = xb + (size_t)(rowBase + wave * 8 + srow) * K_TOT + scol;
  const ushort_t* bBase = wb + (size_t)(colBase + wave * 8 + srow) * K_TOT + scol;

  const int fr = lane & 15;
  const int fg = lane >> 4;
  const int eA = (fg << 4) ^ ((fr & 7) << 4);
  const int frB = fr * 128;
  const char* ldsc = (const char*)lds;

  f32x4 acc[8][4] = {};
  short8 aF[4][2];        // time-shared A m-half
  short8 bF[2][2][2];     // both B n-halves live

  // ---- prologue: K0 fully + first halves of K1; confirm K0, leave 4 in flight ----
  STAGE_B(0, 0, 0);
  STAGE_A(0, 0, 0);
  STAGE_A(0, 0, 1);
  STAGE_B(0, 0, 1);
  STAGE_B(1, 1, 0);
  STAGE_A(1, 1, 0);
  VMCNT(4);
  BAR;

  for (int it = 0; it < 32; ++it) {
    const int T = 2 * it;
    const int k2 = (T + 2) & 63;   // wrap on last iter: staged but never read
    const int k3 = (T + 3) & 63;
    // P1: compute T(buf0) quad(m0,n0); stage second halves of K-tile T+1 -> buf1
    LDA(0, 0); LDB(0, 0);
    STAGE_A(T + 1, 1, 1); STAGE_B(T + 1, 1, 1);
    BAR; QUAD(0, 0); BAR;
    // P2: quad(m0,n1)
    LDB(0, 1);
    BAR; QUAD(0, 1); BAR;
    // P3: quad(m1,n1); stage B(T+2)h0 -> buf0 (B(T) reads done at P2)
    LDA(0, 1);
    STAGE_B(k2, 0, 0);
    BAR; QUAD(1, 1); BAR;
    // P4: quad(m1,n0); stage A(T+2)h0; counted vmcnt confirms K(T+1) for P5
    STAGE_A(k2, 0, 0);
    VMCNT(4);
    BAR; QUAD(1, 0); BAR;
    // P5: compute T+1(buf1) quad(m0,n0); stage remaining K(T+2) halves -> buf0
    LDA(1, 0); LDB(1, 0);
    STAGE_A(k2, 0, 1); STAGE_B(k2, 0, 1);
    BAR; QUAD(0, 0); BAR;
    // P6: quad(m0,n1)
    LDB(1, 1);
    BAR; QUAD(0, 1); BAR;
    // P7: quad(m1,n1); stage B(T+3)h0 -> buf1
    LDA(1, 1);
    STAGE_B(k3, 1, 0);
    BAR; QUAD(1, 1); BAR;
    // P8: quad(m1,n0); stage A(T+3)h0; vmcnt confirms K(T+2) for next P1
    STAGE_A(k3, 1, 0);
    VMCNT(4);
    BAR; QUAD(1, 0); BAR;
  }

  // ---- epilogue: drain outstanding DMAs before repurposing LDS ----
  asm volatile("s_waitcnt vmcnt(0)" ::: "memory");
  BAR;

  float* hs = (float*)lds;          // [256][16] fp32
  float* lbs = hs + 4096;           // [256][16] fp32
  {
    const int g = by >> 2;
    const float* hsrc = hbuf + ((size_t)g * 1024 + (size_t)(by & 3) * 256) * 16;
    const float* lsrc = lorab + ((size_t)g * 4096 + (size_t)colBase) * 16;
    for (int idx = tid; idx < 1024; idx += 512) {
      ((float4*)hs)[idx] = ((const float4*)hsrc)[idx];
      ((float4*)lbs)[idx] = ((const float4*)lsrc)[idx];
    }
  }
  __syncthreads();

  float lbv[4][16];
  float bv[4];
#pragma unroll
  for (int nh = 0; nh < 2; ++nh)
#pragma unroll
    for (int nf = 0; nf < 2; ++nf) {
      const int cl = wn * 64 + nh * 32 + nf * 16 + fr;
      bv[nh * 2 + nf] = bias[colBase + cl];
#pragma unroll
      for (int r = 0; r < 16; ++r) lbv[nh * 2 + nf][r] = lbs[cl * 16 + r];
    }

#pragma unroll
  for (int mh = 0; mh < 2; ++mh)
#pragma unroll
    for (int mf = 0; mf < 4; ++mf)
#pragma unroll
      for (int i = 0; i < 4; ++i) {
        const int rl = wm * 128 + mh * 64 + mf * 16 + fg * 4 + i;
        float hv[16];
#pragma unroll
        for (int r = 0; r < 16; ++r) hv[r] = hs[rl * 16 + r];
        float* orow = out + (size_t)(rowBase + rl) * N_TOT + colBase;
#pragma unroll
        for (int nh = 0; nh < 2; ++nh)
#pragma unroll
          for (int nf = 0; nf < 2; ++nf) {
            float d = 0.f;
#pragma unroll
            for (int r = 0; r < 16; ++r) d += hv[r] * lbv[nh * 2 + nf][r];
            orow[wn * 64 + nh * 32 + nf * 16 + fr] =
                acc[mh * 4 + mf][nh * 2 + nf][i] + bv[nh * 2 + nf] + d;
          }
      }
}

// ---------------- launch ----------------

extern "C" void kernel_launch(void* const* d_in, const int* in_sizes, int n_in,
                              void* d_out, int out_size, void* d_ws, size_t ws_size,
                              hipStream_t stream) {
  const float* x      = (const float*)d_in[0];  // [16384][4096]
  const float* base_w = (const float*)d_in[1];  // [4096][4096]
  const float* base_b = (const float*)d_in[2];  // [4096]
  const float* lora_a = (const float*)d_in[3];  // [16][16][4096]
  const float* lora_b = (const float*)d_in[4];  // [16][4096][16]
  float* out = (float*)d_out;

  // workspace: h (1MB) | w_bf16 (32MB) | x_bf16 (128MB)
  char* ws = (char*)d_ws;
  float* h = (float*)ws;
  ushort_t* wb = (ushort_t*)(ws + (1u << 20));
  ushort_t* xb = (ushort_t*)(ws + (1u << 20) + (32u << 20));

  cvt_bf16_kernel<<<4096, 256, 0, stream>>>(x, xb, (M_TOT * K_TOT) / 8);
  cvt_bf16_kernel<<<2048, 256, 0, stream>>>(base_w, wb, (N_TOT * K_TOT) / 8);
  lora_h_kernel<<<M_TOT / 32, 256, 0, stream>>>(xb, lora_a, h);
  gemm_kernel<<<1024, 512, 0, stream>>>(xb, wb, base_b, h, lora_b, out);
}

// Round 3
// 725.792 us; speedup vs baseline: 1.0632x; 1.0632x over previous
//
#include <hip/hip_runtime.h>

typedef unsigned short ushort_t;
typedef short short8 __attribute__((ext_vector_type(8)));
typedef float f32x4 __attribute__((ext_vector_type(4)));

#define M_TOT 16384
#define N_TOT 4096
#define K_TOT 4096

// ---------------- helpers ----------------

__device__ __forceinline__ unsigned short f2bf(float f) {
  unsigned int u = __float_as_uint(f);
  unsigned int r = (u + 0x7fffu + ((u >> 16) & 1u)) >> 16;  // RNE
  return (unsigned short)r;
}

__device__ __forceinline__ void gld_lds16(const void* g, void* l) {
  __builtin_amdgcn_global_load_lds(
      (__attribute__((address_space(1))) const unsigned int*)g,
      (__attribute__((address_space(3))) unsigned int*)l, 16, 0, 0);
}

// ---------------- fp32 -> bf16 convert (for base_w) ----------------

__global__ void cvt_bf16_kernel(const float* __restrict__ src,
                                ushort_t* __restrict__ dst, int n8) {
  for (long long i = (long long)blockIdx.x * 256 + threadIdx.x; i < n8;
       i += (long long)gridDim.x * 256) {
    const float4* s = (const float4*)src + i * 2;
    float4 a = s[0], b = s[1];
    union { ushort_t u[8]; uint4 v; } o;
    o.u[0] = f2bf(a.x); o.u[1] = f2bf(a.y); o.u[2] = f2bf(a.z); o.u[3] = f2bf(a.w);
    o.u[4] = f2bf(b.x); o.u[5] = f2bf(b.y); o.u[6] = f2bf(b.z); o.u[7] = f2bf(b.w);
    ((uint4*)dst)[i] = o.v;
  }
}

// ---------------- fused: xb = bf16(x); h[g][m][r] = sum_i x[m][i]*A[g][r][i] ----------------
// One pass over x. 8 rows/wave, 32 rows/block, 512 blocks.

__global__ __launch_bounds__(256) void cvtx_h_kernel(
    const float* __restrict__ x, const float* __restrict__ lora_a,
    ushort_t* __restrict__ xb, float* __restrict__ h) {
  const int lane = threadIdx.x & 63;
  const int wave = threadIdx.x >> 6;
  const int rowBase = blockIdx.x * 32 + wave * 8;  // 32 | 1024, no group crossing
  const int g = rowBase >> 10;
  const float* A = lora_a + (size_t)g * 16 * K_TOT;

  float acc[8][16] = {};
  for (int i = lane * 4; i < K_TOT; i += 256) {
    float4 xv[8];
#pragma unroll
    for (int r = 0; r < 8; ++r) {
      xv[r] = *(const float4*)(x + (size_t)(rowBase + r) * K_TOT + i);
      union { ushort_t u[4]; uint2 d; } o;
      o.u[0] = f2bf(xv[r].x); o.u[1] = f2bf(xv[r].y);
      o.u[2] = f2bf(xv[r].z); o.u[3] = f2bf(xv[r].w);
      *(uint2*)(xb + (size_t)(rowBase + r) * K_TOT + i) = o.d;
    }
#pragma unroll
    for (int t = 0; t < 16; ++t) {
      float4 av = *(const float4*)(A + (size_t)t * K_TOT + i);
#pragma unroll
      for (int r = 0; r < 8; ++r)
        acc[r][t] += xv[r].x * av.x + xv[r].y * av.y + xv[r].z * av.z + xv[r].w * av.w;
    }
  }
#pragma unroll
  for (int r = 0; r < 8; ++r)
#pragma unroll
    for (int t = 0; t < 16; ++t) {
      float v = acc[r][t];
      v += __shfl_xor(v, 32); v += __shfl_xor(v, 16); v += __shfl_xor(v, 8);
      v += __shfl_xor(v, 4);  v += __shfl_xor(v, 2);  v += __shfl_xor(v, 1);
      if (lane == 0) {
        int mloc = (rowBase + r) & 1023;
        h[((size_t)g << 14) + (size_t)mloc * 16 + t] = v;
      }
    }
}

// ---------------- main GEMM: out = Xbf*Wbf^T + bias + h*lb^T ----------------
// 256x256 tile, BK=64, 8 waves (2Mx4N), 8-phase counted-vmcnt schedule.
// A staged 5-6 phases ahead (HBM latency), B 4 phases (L3-hot). vmcnt(8) at P4/P8.

#define STAGE_A(kt, buf, hh) do {                                              \
    const ushort_t* _g = aBase + (size_t)((hh) * 128) * K_TOT + (size_t)(kt) * 64; \
    gld_lds16(_g, &lds[(buf) * 16384 + (hh) * 8192 + wave * 512]);             \
    gld_lds16(_g + (size_t)64 * K_TOT,                                         \
              &lds[(buf) * 16384 + (hh) * 8192 + 4096 + wave * 512]);          \
  } while (0)
#define STAGE_B(kt, buf, hh) do {                                              \
    const ushort_t* _g = bBase + (size_t)((hh) * 128) * K_TOT + (size_t)(kt) * 64; \
    gld_lds16(_g, &lds[32768 + (buf) * 16384 + (hh) * 8192 + wave * 512]);     \
    gld_lds16(_g + (size_t)64 * K_TOT,                                         \
              &lds[32768 + (buf) * 16384 + (hh) * 8192 + 4096 + wave * 512]);  \
  } while (0)

#define LDA(buf, mh) do {                                                      \
    _Pragma("unroll") for (int mf = 0; mf < 4; ++mf)                           \
    _Pragma("unroll") for (int kk = 0; kk < 2; ++kk)                           \
      aF[mh][mf][kk] = *(const short8*)(ldsc + (buf) * 32768 + wm * 16384 +    \
                                        (mh) * 8192 + mf * 2048 + frB +        \
                                        (eA ^ (kk << 6)));                     \
  } while (0)
#define LDB(buf, nh) do {                                                      \
    _Pragma("unroll") for (int nf = 0; nf < 2; ++nf)                           \
    _Pragma("unroll") for (int kk = 0; kk < 2; ++kk)                           \
      bF[nf][kk] = *(const short8*)(ldsc + 65536 + (buf) * 32768 +             \
                                    wn * 8192 + (nh) * 4096 + nf * 2048 +      \
                                    frB + (eA ^ (kk << 6)));                   \
  } while (0)

#define QUAD(mh, nh) do {                                                      \
    __builtin_amdgcn_s_setprio(1);                                             \
    _Pragma("unroll") for (int mf = 0; mf < 4; ++mf)                           \
    _Pragma("unroll") for (int nf = 0; nf < 2; ++nf)                           \
    _Pragma("unroll") for (int kk = 0; kk < 2; ++kk)                           \
      acc[(mh) * 4 + mf][(nh) * 2 + nf] = __builtin_amdgcn_mfma_f32_16x16x32_bf16( \
          aF[mh][mf][kk], bF[nf][kk], acc[(mh) * 4 + mf][(nh) * 2 + nf], 0, 0, 0); \
    __builtin_amdgcn_s_setprio(0);                                             \
  } while (0)

#define BAR __builtin_amdgcn_s_barrier()
#define VMCNT(n) asm volatile("s_waitcnt vmcnt(" #n ")" ::: "memory")

__global__ __launch_bounds__(512, 2) void gemm_kernel(
    const ushort_t* __restrict__ xb,    // [M][K] bf16
    const ushort_t* __restrict__ wb,    // [N][K] bf16
    const float* __restrict__ bias,     // [N]
    const float* __restrict__ hbuf,     // [16][1024][16] fp32
    const float* __restrict__ lorab,    // [16][4096][16] fp32
    float* __restrict__ out) {          // [M][N] fp32
  __shared__ __align__(16) ushort_t lds[65536];  // 128 KiB

  const int tid = threadIdx.x;
  const int lane = tid & 63;
  const int wave = tid >> 6;
  const int wm = wave >> 2;             // 0..1
  const int wn = wave & 3;              // 0..3
  const int bid = blockIdx.x;
  const int swz = (bid & 7) * 128 + (bid >> 3);   // XCD-aware, bijective (1024%8==0)
  const int by = swz >> 4;              // 0..63 row tile
  const int bx = swz & 15;              // 0..15 col tile
  const int rowBase = by * 256;
  const int colBase = bx * 256;

  const int srow = lane >> 3;
  const int scol = ((lane & 7) ^ srow) << 3;     // inverse-swizzled global col
  const ushort_t* aBase = xb + (size_t)(rowBase + wave * 8 + srow) * K_TOT + scol;
  const ushort_t* bBase = wb + (size_t)(colBase + wave * 8 + srow) * K_TOT + scol;

  const int fr = lane & 15;
  const int fg = lane >> 4;
  const int eA = (fg << 4) ^ ((fr & 7) << 4);
  const int frB = fr * 128;
  const char* ldsc = (const char*)lds;

  f32x4 acc[8][4] = {};
  short8 aF[2][4][2];     // BOTH m-quarters live (frees A LDS regions after P2/P6)
  short8 bF[2][2];        // one n-half at a time

  // ---- prologue: stage K0 + K1 fully; confirm K0, leave K1's 8 in flight ----
  STAGE_A(0, 0, 0); STAGE_A(0, 0, 1); STAGE_B(0, 0, 0); STAGE_B(0, 0, 1);
  STAGE_A(1, 1, 0); STAGE_A(1, 1, 1); STAGE_B(1, 1, 0); STAGE_B(1, 1, 1);
  VMCNT(8);
  BAR;

  for (int it = 0; it < 32; ++it) {
    const int k2 = (2 * it + 2) & 63;   // wrap on last iters: staged, never read
    const int k3 = (2 * it + 3) & 63;
    // P1: tile T (buf0) quad(m0,n0)
    LDA(0, 0); LDB(0, 0);
    BAR; QUAD(0, 0); BAR;
    // P2: quad(m1,n0)  [A buf0 reads complete]
    LDA(0, 1);
    BAR; QUAD(1, 0); BAR;
    // P3: quad(m1,n1); stage A(T+2) -> buf0  [B buf0 reads complete after this]
    LDB(0, 1);
    STAGE_A(k2, 0, 0); STAGE_A(k2, 0, 1);
    BAR; QUAD(1, 1); BAR;
    // P4: quad(m0,n1); stage B(T+2) -> buf0; confirm K(T+1) for P5
    STAGE_B(k2, 0, 0); STAGE_B(k2, 0, 1);
    VMCNT(8);
    BAR; QUAD(0, 1); BAR;
    // P5: tile T+1 (buf1) quad(m0,n0)
    LDA(1, 0); LDB(1, 0);
    BAR; QUAD(0, 0); BAR;
    // P6: quad(m1,n0)
    LDA(1, 1);
    BAR; QUAD(1, 0); BAR;
    // P7: quad(m1,n1); stage A(T+3) -> buf1
    LDB(1, 1);
    STAGE_A(k3, 1, 0); STAGE_A(k3, 1, 1);
    BAR; QUAD(1, 1); BAR;
    // P8: quad(m0,n1); stage B(T+3) -> buf1; confirm K(T+2) for next P1
    STAGE_B(k3, 1, 0); STAGE_B(k3, 1, 1);
    VMCNT(8);
    BAR; QUAD(0, 1); BAR;
  }

  // ---- epilogue: drain DMAs before repurposing LDS ----
  asm volatile("s_waitcnt vmcnt(0)" ::: "memory");
  BAR;

  float* hs = (float*)lds;          // [256][16] fp32
  float* lbs = hs + 4096;           // [256][16] fp32
  {
    const int g = by >> 2;
    const float* hsrc = hbuf + ((size_t)g * 1024 + (size_t)(by & 3) * 256) * 16;
    const float* lsrc = lorab + ((size_t)g * 4096 + (size_t)colBase) * 16;
    for (int idx = tid; idx < 1024; idx += 512) {
      ((float4*)hs)[idx] = ((const float4*)hsrc)[idx];
      ((float4*)lbs)[idx] = ((const float4*)lsrc)[idx];
    }
  }
  __syncthreads();

  float lbv[4][16];
  float bv[4];
#pragma unroll
  for (int nh = 0; nh < 2; ++nh)
#pragma unroll
    for (int nf = 0; nf < 2; ++nf) {
      const int cl = wn * 64 + nh * 32 + nf * 16 + fr;
      bv[nh * 2 + nf] = bias[colBase + cl];
#pragma unroll
      for (int r = 0; r < 16; ++r) lbv[nh * 2 + nf][r] = lbs[cl * 16 + r];
    }

#pragma unroll
  for (int mh = 0; mh < 2; ++mh)
#pragma unroll
    for (int mf = 0; mf < 4; ++mf)
#pragma unroll
      for (int i = 0; i < 4; ++i) {
        const int rl = wm * 128 + mh * 64 + mf * 16 + fg * 4 + i;
        float hv[16];
#pragma unroll
        for (int r = 0; r < 16; ++r) hv[r] = hs[rl * 16 + r];
        float* orow = out + (size_t)(rowBase + rl) * N_TOT + colBase;
#pragma unroll
        for (int nh = 0; nh < 2; ++nh)
#pragma unroll
          for (int nf = 0; nf < 2; ++nf) {
            float d = 0.f;
#pragma unroll
            for (int r = 0; r < 16; ++r) d += hv[r] * lbv[nh * 2 + nf][r];
            orow[wn * 64 + nh * 32 + nf * 16 + fr] =
                acc[mh * 4 + mf][nh * 2 + nf][i] + bv[nh * 2 + nf] + d;
          }
      }
}

// ---------------- launch ----------------

extern "C" void kernel_launch(void* const* d_in, const int* in_sizes, int n_in,
                              void* d_out, int out_size, void* d_ws, size_t ws_size,
                              hipStream_t stream) {
  const float* x      = (const float*)d_in[0];  // [16384][4096]
  const float* base_w = (const float*)d_in[1];  // [4096][4096]
  const float* base_b = (const float*)d_in[2];  // [4096]
  const float* lora_a = (const float*)d_in[3];  // [16][16][4096]
  const float* lora_b = (const float*)d_in[4];  // [16][4096][16]
  float* out = (float*)d_out;

  // workspace: h (1MB) | w_bf16 (32MB) | x_bf16 (128MB)
  char* ws = (char*)d_ws;
  float* h = (float*)ws;
  ushort_t* wb = (ushort_t*)(ws + (1u << 20));
  ushort_t* xb = (ushort_t*)(ws + (1u << 20) + (32u << 20));

  cvt_bf16_kernel<<<2048, 256, 0, stream>>>(base_w, wb, (N_TOT * K_TOT) / 8);
  cvtx_h_kernel<<<M_TOT / 32, 256, 0, stream>>>(x, lora_a, xb, h);
  gemm_kernel<<<1024, 512, 0, stream>>>(xb, wb, base_b, h, lora_b, out);
}

// Round 5
// 623.552 us; speedup vs baseline: 1.2376x; 1.1640x over previous
//
#include <hip/hip_runtime.h>

typedef unsigned short ushort_t;
typedef short short8 __attribute__((ext_vector_type(8)));
typedef float f32x4 __attribute__((ext_vector_type(4)));

#define M_TOT 16384
#define N_TOT 4096
#define K_TOT 4096

// ---------------- helpers ----------------

__device__ __forceinline__ unsigned short f2bf(float f) {
  unsigned int u = __float_as_uint(f);
  unsigned int r = (u + 0x7fffu + ((u >> 16) & 1u)) >> 16;  // RNE
  return (unsigned short)r;
}

__device__ __forceinline__ void gld_lds16(const void* g, void* l) {
  __builtin_amdgcn_global_load_lds(
      (__attribute__((address_space(1))) const unsigned int*)g,
      (__attribute__((address_space(3))) unsigned int*)l, 16, 0, 0);
}

// ---------------- fused aux: W->bf16 (blocks 0..511), X->bf16 + h (512..1535) ----------------

__global__ __launch_bounds__(256) void aux_kernel(
    const float* __restrict__ x, const float* __restrict__ base_w,
    const float* __restrict__ lora_a, ushort_t* __restrict__ xb,
    ushort_t* __restrict__ wb, float* __restrict__ h) {
  const int tid = threadIdx.x;
  if (blockIdx.x < 512) {
    // convert base_w: 64MB fp32 -> 32MB bf16, 32768 floats (8192 float4) per block
    const float4* src = (const float4*)base_w + (size_t)blockIdx.x * 8192;
    uint4* dst = (uint4*)wb + (size_t)blockIdx.x * 4096;   // FIX: was *1024
#pragma unroll 4
    for (int j = 0; j < 16; ++j) {
      int p = j * 256 + tid;
      float4 a = src[p * 2], b = src[p * 2 + 1];
      union { ushort_t u[8]; uint4 v; } o;
      o.u[0] = f2bf(a.x); o.u[1] = f2bf(a.y); o.u[2] = f2bf(a.z); o.u[3] = f2bf(a.w);
      o.u[4] = f2bf(b.x); o.u[5] = f2bf(b.y); o.u[6] = f2bf(b.z); o.u[7] = f2bf(b.w);
      dst[p] = o.v;
    }
    return;
  }
  // X part: 16 rows/block, 4 rows/wave; h[g][m][r] = sum_i x[m][i]*A[g][r][i]
  const int lane = tid & 63;
  const int wave = tid >> 6;
  const int rowBase = (blockIdx.x - 512) * 16 + wave * 4;  // 16 | 1024: no group crossing
  const int g = rowBase >> 10;
  const float* A = lora_a + (size_t)g * 16 * K_TOT;

  float acc[4][16] = {};
  for (int i = lane * 4; i < K_TOT; i += 256) {
    float4 xv[4];
#pragma unroll
    for (int r = 0; r < 4; ++r) {
      xv[r] = *(const float4*)(x + (size_t)(rowBase + r) * K_TOT + i);
      union { ushort_t u[4]; uint2 d; } o;
      o.u[0] = f2bf(xv[r].x); o.u[1] = f2bf(xv[r].y);
      o.u[2] = f2bf(xv[r].z); o.u[3] = f2bf(xv[r].w);
      *(uint2*)(xb + (size_t)(rowBase + r) * K_TOT + i) = o.d;
    }
#pragma unroll
    for (int t = 0; t < 16; ++t) {
      float4 av = *(const float4*)(A + (size_t)t * K_TOT + i);
#pragma unroll
      for (int r = 0; r < 4; ++r)
        acc[r][t] += xv[r].x * av.x + xv[r].y * av.y + xv[r].z * av.z + xv[r].w * av.w;
    }
  }
#pragma unroll
  for (int r = 0; r < 4; ++r)
#pragma unroll
    for (int t = 0; t < 16; ++t) {
      float v = acc[r][t];
      v += __shfl_xor(v, 32); v += __shfl_xor(v, 16); v += __shfl_xor(v, 8);
      v += __shfl_xor(v, 4);  v += __shfl_xor(v, 2);  v += __shfl_xor(v, 1);
      if (lane == 0) {
        int mloc = (rowBase + r) & 1023;
        h[((size_t)g << 14) + (size_t)mloc * 16 + t] = v;
      }
    }
}

// ---------------- main GEMM: out = Xbf*Wbf^T + bias + h*lb^T ----------------
// 256x256 tile, BK=64, 8 waves (2Mx4N), 8-phase, ONE half-tile staged per phase,
// vmcnt(4) at P4/P8.

#define STAGE_A(kt, buf, hh) do {                                              \
    const ushort_t* _g = aBase + (size_t)((hh) * 128) * K_TOT + (size_t)(kt) * 64; \
    gld_lds16(_g, &lds[(buf) * 16384 + (hh) * 8192 + wave * 512]);             \
    gld_lds16(_g + (size_t)64 * K_TOT,                                         \
              &lds[(buf) * 16384 + (hh) * 8192 + 4096 + wave * 512]);          \
  } while (0)
#define STAGE_B(kt, buf, hh) do {                                              \
    const ushort_t* _g = bBase + (size_t)((hh) * 128) * K_TOT + (size_t)(kt) * 64; \
    gld_lds16(_g, &lds[32768 + (buf) * 16384 + (hh) * 8192 + wave * 512]);     \
    gld_lds16(_g + (size_t)64 * K_TOT,                                         \
              &lds[32768 + (buf) * 16384 + (hh) * 8192 + 4096 + wave * 512]);  \
  } while (0)

#define LDA(buf, mh) do {                                                      \
    _Pragma("unroll") for (int mf = 0; mf < 4; ++mf)                           \
    _Pragma("unroll") for (int kk = 0; kk < 2; ++kk)                           \
      aF[mf][kk] = *(const short8*)(ldsc + (buf) * 32768 + wm * 16384 +        \
                                    (mh) * 8192 + mf * 2048 + frB +            \
                                    (eA ^ (kk << 6)));                         \
  } while (0)
#define LDB(buf, nh) do {                                                      \
    _Pragma("unroll") for (int nf = 0; nf < 2; ++nf)                           \
    _Pragma("unroll") for (int kk = 0; kk < 2; ++kk)                           \
      bF[nh][nf][kk] = *(const short8*)(ldsc + 65536 + (buf) * 32768 +         \
                                        wn * 8192 + (nh) * 4096 + nf * 2048 +  \
                                        frB + (eA ^ (kk << 6)));               \
  } while (0)

#define QUAD(mh, nh) do {                                                      \
    __builtin_amdgcn_s_setprio(1);                                             \
    _Pragma("unroll") for (int mf = 0; mf < 4; ++mf)                           \
    _Pragma("unroll") for (int nf = 0; nf < 2; ++nf)                           \
    _Pragma("unroll") for (int kk = 0; kk < 2; ++kk)                           \
      acc[(mh) * 4 + mf][(nh) * 2 + nf] = __builtin_amdgcn_mfma_f32_16x16x32_bf16( \
          aF[mf][kk], bF[nh][nf][kk], acc[(mh) * 4 + mf][(nh) * 2 + nf], 0, 0, 0); \
    __builtin_amdgcn_s_setprio(0);                                             \
  } while (0)

#define BAR __builtin_amdgcn_s_barrier()
#define VMCNT(n) asm volatile("s_waitcnt vmcnt(" #n ")" ::: "memory")

__global__ __launch_bounds__(512, 2) void gemm_kernel(
    const ushort_t* __restrict__ xb,    // [M][K] bf16
    const ushort_t* __restrict__ wb,    // [N][K] bf16
    const float* __restrict__ bias,     // [N]
    const float* __restrict__ hbuf,     // [16][1024][16] fp32
    const float* __restrict__ lorab,    // [16][4096][16] fp32
    float* __restrict__ out) {          // [M][N] fp32
  __shared__ __align__(16) ushort_t lds[65536];  // 128 KiB

  const int tid = threadIdx.x;
  const int lane = tid & 63;
  const int wave = tid >> 6;
  const int wm = wave >> 2;             // 0..1
  const int wn = wave & 3;              // 0..3
  const int bid = blockIdx.x;
  const int swz = (bid & 7) * 128 + (bid >> 3);   // XCD-aware, bijective (1024%8==0)
  const int by = swz >> 4;              // 0..63 row tile
  const int bx = swz & 15;              // 0..15 col tile
  const int rowBase = by * 256;
  const int colBase = bx * 256;

  const int srow = lane >> 3;
  const int scol = ((lane & 7) ^ srow) << 3;     // inverse-swizzled global col
  const ushort_t* aBase = xb + (size_t)(rowBase + wave * 8 + srow) * K_TOT + scol;
  const ushort_t* bBase = wb + (size_t)(colBase + wave * 8 + srow) * K_TOT + scol;

  const int fr = lane & 15;
  const int fg = lane >> 4;
  const int eA = (fg << 4) ^ ((fr & 7) << 4);
  const int frB = fr * 128;
  const char* ldsc = (const char*)lds;

  f32x4 acc[8][4] = {};
  short8 aF[4][2];        // one m-half at a time
  short8 bF[2][2][2];     // both n-halves live

  // ---- prologue: K0 fully + B(K1); confirm K0 (drain to 4 = B(K1) in flight) ----
  STAGE_A(0, 0, 0); STAGE_A(0, 0, 1);
  STAGE_B(0, 0, 0); STAGE_B(0, 0, 1);
  STAGE_B(1, 1, 0); STAGE_B(1, 1, 1);
  VMCNT(4);
  BAR;

  for (int it = 0; it < 32; ++it) {
    const int k1 = 2 * it + 1;          // <= 63, no wrap
    const int k2 = (2 * it + 2) & 63;   // last iter: staged, never read
    const int k3 = (2 * it + 3) & 63;
    // P1: tile T (buf0) quad(m0,n0); stage A(T+1)h0 -> buf1
    LDA(0, 0); LDB(0, 0);
    STAGE_A(k1, 1, 0);
    BAR; QUAD(0, 0); BAR;
    // P2: quad(m0,n1); stage A(T+1)h1
    LDB(0, 1);
    STAGE_A(k1, 1, 1);
    BAR; QUAD(0, 1); BAR;
    // P3: quad(m1,n1); stage B(T+2)h0 -> buf0 (B buf0 reads done at P2)
    LDA(0, 1);
    STAGE_B(k2, 0, 0);
    BAR; QUAD(1, 1); BAR;
    // P4: quad(m1,n0); stage B(T+2)h1; vmcnt(4) confirms tile T+1 for P5
    STAGE_B(k2, 0, 1);
    VMCNT(4);
    BAR; QUAD(1, 0); BAR;
    // P5: tile T+1 (buf1) quad(m0,n0); stage A(T+2)h0 -> buf0 (A buf0 done at P3)
    LDA(1, 0); LDB(1, 0);
    STAGE_A(k2, 0, 0);
    BAR; QUAD(0, 0); BAR;
    // P6: quad(m0,n1); stage A(T+2)h1
    LDB(1, 1);
    STAGE_A(k2, 0, 1);
    BAR; QUAD(0, 1); BAR;
    // P7: quad(m1,n1); stage B(T+3)h0 -> buf1 (B buf1 reads done at P6)
    LDA(1, 1);
    STAGE_B(k3, 1, 0);
    BAR; QUAD(1, 1); BAR;
    // P8: quad(m1,n0); stage B(T+3)h1; vmcnt(4) confirms tile T+2 for next P1
    STAGE_B(k3, 1, 1);
    VMCNT(4);
    BAR; QUAD(1, 0); BAR;
  }

  // ---- epilogue: drain DMAs before repurposing LDS ----
  asm volatile("s_waitcnt vmcnt(0)" ::: "memory");
  BAR;

  float* hs = (float*)lds;          // [256][16] fp32
  float* lbs = hs + 4096;           // [256][16] fp32
  {
    const int g = by >> 2;
    const float* hsrc = hbuf + ((size_t)g * 1024 + (size_t)(by & 3) * 256) * 16;
    const float* lsrc = lorab + ((size_t)g * 4096 + (size_t)colBase) * 16;
    for (int idx = tid; idx < 1024; idx += 512) {
      ((float4*)hs)[idx] = ((const float4*)hsrc)[idx];
      ((float4*)lbs)[idx] = ((const float4*)lsrc)[idx];
    }
  }
  __syncthreads();

  float lbv[4][16];
  float bv[4];
#pragma unroll
  for (int nh = 0; nh < 2; ++nh)
#pragma unroll
    for (int nf = 0; nf < 2; ++nf) {
      const int cl = wn * 64 + nh * 32 + nf * 16 + fr;
      bv[nh * 2 + nf] = bias[colBase + cl];
#pragma unroll
      for (int r = 0; r < 16; ++r) lbv[nh * 2 + nf][r] = lbs[cl * 16 + r];
    }

#pragma unroll
  for (int mh = 0; mh < 2; ++mh)
#pragma unroll
    for (int mf = 0; mf < 4; ++mf)
#pragma unroll
      for (int i = 0; i < 4; ++i) {
        const int rl = wm * 128 + mh * 64 + mf * 16 + fg * 4 + i;
        float hv[16];
#pragma unroll
        for (int r = 0; r < 16; ++r) hv[r] = hs[rl * 16 + r];
        float* orow = out + (size_t)(rowBase + rl) * N_TOT + colBase;
#pragma unroll
        for (int nh = 0; nh < 2; ++nh)
#pragma unroll
          for (int nf = 0; nf < 2; ++nf) {
            float d = 0.f;
#pragma unroll
            for (int r = 0; r < 16; ++r) d += hv[r] * lbv[nh * 2 + nf][r];
            orow[wn * 64 + nh * 32 + nf * 16 + fr] =
                acc[mh * 4 + mf][nh * 2 + nf][i] + bv[nh * 2 + nf] + d;
          }
      }
}

// ---------------- launch ----------------

extern "C" void kernel_launch(void* const* d_in, const int* in_sizes, int n_in,
                              void* d_out, int out_size, void* d_ws, size_t ws_size,
                              hipStream_t stream) {
  const float* x      = (const float*)d_in[0];  // [16384][4096]
  const float* base_w = (const float*)d_in[1];  // [4096][4096]
  const float* base_b = (const float*)d_in[2];  // [4096]
  const float* lora_a = (const float*)d_in[3];  // [16][16][4096]
  const float* lora_b = (const float*)d_in[4];  // [16][4096][16]
  float* out = (float*)d_out;

  // workspace: h (1MB) | w_bf16 (32MB) | x_bf16 (128MB)
  char* ws = (char*)d_ws;
  float* h = (float*)ws;
  ushort_t* wb = (ushort_t*)(ws + (1u << 20));
  ushort_t* xb = (ushort_t*)(ws + (1u << 20) + (32u << 20));

  aux_kernel<<<1536, 256, 0, stream>>>(x, base_w, lora_a, xb, wb, h);
  gemm_kernel<<<1024, 512, 0, stream>>>(xb, wb, base_b, h, lora_b, out);
}